// Round 1
// baseline (1040.142 us; speedup 1.0000x reference)
//
#include <hip/hip_runtime.h>
#include <math.h>

// AdaptiveAvgPool2D channels-last:
//   in  [B=16, H=225, W=225, C=256] fp32
//   out [B=16, OX=7,  OY=7,  C=256] fp32
// Window o over dim of size N=225, out=7:
//   start = (int)( o * (float)(225/7) )        (fp32 trunc, matches numpy)
//   end   = (int)ceilf( (o+1) * (float)(225/7) )
// -> every window is 33 wide, starts at 32*o. Weight = 1/(nx*ny).

#define BB 16
#define HH 225
#define WW 225
#define OX 7
#define OY 7
#define NW 8   // waves per block

__global__ __launch_bounds__(512)
void AdaptivePooling2D_88768384074199_kernel(const float4* __restrict__ in,
                                             float4* __restrict__ out) {
    __shared__ float4 smem[NW][64];

    const int bid = blockIdx.x;
    const int oy = bid % OY;
    const int ox = (bid / OY) % OX;
    const int b  = bid / (OY * OX);

    // Reproduce TF/numpy fp32 index math exactly.
    const float scale_h = (float)HH / (float)OX;
    const float scale_w = (float)WW / (float)OY;
    const int xs = (int)((float)ox * scale_h);
    const int xe = (int)ceilf((float)(ox + 1) * scale_h);
    const int ys = (int)((float)oy * scale_w);
    const int ye = (int)ceilf((float)(oy + 1) * scale_w);
    const int nx = xe - xs;
    const int ny = ye - ys;
    const int npix = nx * ny;

    const int lane = threadIdx.x & 63;   // channel chunk (64 x float4 = 256 ch)
    const int wave = threadIdx.x >> 6;   // splits the window pixels

    // Base pointer: pixel (xs, ys), this lane's channel chunk.
    const float4* __restrict__ src =
        in + (((size_t)b * HH + xs) * WW + ys) * 64 + lane;

    float4 acc = make_float4(0.f, 0.f, 0.f, 0.f);

    #pragma unroll 4
    for (int p = wave; p < npix; p += NW) {
        const int dx = p / ny;           // window row
        const int dy = p - dx * ny;      // window col
        const float4 v = src[((size_t)dx * WW + dy) * 64];
        acc.x += v.x; acc.y += v.y; acc.z += v.z; acc.w += v.w;
    }

    smem[wave][lane] = acc;
    __syncthreads();

    if (threadIdx.x < 64) {
        float4 s = smem[0][lane];
        #pragma unroll
        for (int w = 1; w < NW; ++w) {
            const float4 t = smem[w][lane];
            s.x += t.x; s.y += t.y; s.z += t.z; s.w += t.w;
        }
        const float wgt = 1.0f / ((float)nx * (float)ny);
        s.x *= wgt; s.y *= wgt; s.z *= wgt; s.w *= wgt;
        out[(((size_t)b * OX + ox) * OY + oy) * 64 + lane] = s;
    }
}

extern "C" void kernel_launch(void* const* d_in, const int* in_sizes, int n_in,
                              void* d_out, int out_size, void* d_ws, size_t ws_size,
                              hipStream_t stream) {
    (void)in_sizes; (void)n_in; (void)d_ws; (void)ws_size; (void)out_size;
    const float4* in = (const float4*)d_in[0];
    float4* out = (float4*)d_out;
    const int grid = BB * OX * OY;   // 784 blocks, one per output pixel
    AdaptivePooling2D_88768384074199_kernel<<<grid, 512, 0, stream>>>(in, out);
}